// Round 4
// baseline (112569.067 us; speedup 1.0000x reference)
//
#include <hip/hip_runtime.h>
#include <hip/hip_cooperative_groups.h>
#include <math.h>

namespace cg = cooperative_groups;

#define T_LEN 512
#define B_SZ  128
#define C_IN  128
#define H_SZ  512
#define G4    2048
#define POFF  262144   // 4*128*512 parity stride

typedef _Float16 half8 __attribute__((ext_vector_type(8)));
typedef float    float4v __attribute__((ext_vector_type(4)));

struct PP {
  const _Float16 *xT;                  // [T][B][C]
  const _Float16 *ew0, *ewr, *ewh;     // j-major fp16 weights
  const _Float16 *dw0, *dwr, *dwh;
  const float* bcomb;                  // [8][2048]
  _Float16* y0;                        // [T][B][1024]
  _Float16* hst;                       // [2][4][B][H]
  float*    cst;                       // [2][4][B][H]
};

// Stage this block's 16 j-rows of a weight segment into LDS fragment layout:
// WL[(k>>5)*512 + col*32 + (k&31)], col c -> j = (c>>2)*512 + jh0 + (c&3).
__device__ __forceinline__ void stage_w(_Float16* WL, const _Float16* Wg, long stride,
                                        int K, int kbase, int jh0, int tid) {
  const int c = tid & 15, kg = tid >> 4;
  const _Float16* src = Wg + (long)((c >> 2) * 512 + jh0 + (c & 3)) * stride;
  for (int k = kg * 8; k < K; k += 128) {
    const half8 v = *(const half8*)(src + k);
    const int kk = kbase + k;
    *(half8*)(WL + (kk >> 5) * 512 + c * 32 + (kk & 31)) = v;
  }
}

// One LSTM step for this block's (MTS*16 rows x 16 gate-cols): MFMA over up to
// 3 A segments (B from LDS, 2 interleaved acc chains), then fused cell update.
template <int MTS>
__device__ __forceinline__ void do_step(const _Float16* WL,
    const _Float16* A0, long s0, int n0,
    const _Float16* A1, long s1, int n1,
    const _Float16* A2, long s2, int n2,
    int mbase, int jh0, int slot, int ld, int p,
    _Float16* yout, int ydir, const PP& P, int lane) {
  const int c16 = lane & 15, quad = lane >> 4;
  float4v acc[MTS][2];
  #pragma unroll
  for (int mt = 0; mt < MTS; ++mt) {
    acc[mt][0] = {0.f, 0.f, 0.f, 0.f};
    acc[mt][1] = {0.f, 0.f, 0.f, 0.f};
  }

  const _Float16* As[3] = {A0, A1, A2};
  const long Ss[3] = {s0, s1, s2};
  const int  Ns[3] = {n0, n1, n2};
  const _Float16* wbase = WL + c16 * 32 + quad * 8;

  int kc = 0;
  for (int s = 0; s < 3; ++s) {
    const int nch = Ns[s];
    if (nch == 0) break;
    const _Float16* ap[MTS];
    #pragma unroll
    for (int mt = 0; mt < MTS; ++mt)
      ap[mt] = As[s] + (long)(mbase + mt * 16 + c16) * Ss[s] + quad * 8;
    #pragma unroll 4
    for (int ck = 0; ck < nch; ++ck) {
      const half8 b = *(const half8*)(wbase + (kc + ck) * 512);
      const int chain = (kc + ck) & 1;
      #pragma unroll
      for (int mt = 0; mt < MTS; ++mt) {
        const half8 a = *(const half8*)(ap[mt] + ck * 32);
        acc[mt][chain] = __builtin_amdgcn_mfma_f32_16x16x32_f16(a, b, acc[mt][chain], 0, 0, 0);
      }
    }
    kc += nch;
  }

  // ---- epilogue: col c=(lane&15) -> gate=c>>2, jh=jh0+(c&3); row=quad*4+reg.
  const int jl = lane & 3;
  const int jh = jh0 + jl;
  const bool wr = (lane & 12) == 0;
  const float* bias = P.bcomb + slot * 2048;
  float bi = 0.f, bff = 0.f, bg = 0.f, bo = 0.f;
  if (wr) { bi = bias[jh]; bff = bias[512 + jh]; bg = bias[1024 + jh]; bo = bias[1536 + jh]; }
  const int sbase = (lane & 48) | jl;
  #pragma unroll
  for (int mt = 0; mt < MTS; ++mt) {
    #pragma unroll
    for (int r = 0; r < 4; ++r) {
      const float v = acc[mt][0][r] + acc[mt][1][r];
      const float iv = __shfl(v, sbase);
      const float fv = __shfl(v, sbase | 4);
      const float gv = __shfl(v, sbase | 8);
      const float ov = __shfl(v, sbase | 12);
      if (wr) {
        const int m = mbase + mt * 16 + quad * 4 + r;
        const long bh = (long)m * H_SZ + jh;
        const float ig = iv + bi, fg = fv + bff, gg = gv + bg, og = ov + bo;
        const float si = 1.0f / (1.0f + __expf(-ig));
        const float sf = 1.0f / (1.0f + __expf(-fg));
        const float so = 1.0f / (1.0f + __expf(-og));
        const float eg = __expf(2.0f * gg);
        const float tg = (eg - 1.0f) / (eg + 1.0f);
        const float c2 = sf * P.cst[p * POFF + ld * 65536 + bh] + si * tg;
        const float ec = __expf(2.0f * c2);
        const float tc = (ec - 1.0f) / (ec + 1.0f);
        const float h2 = so * tc;
        P.cst[(1 - p) * POFF + ld * 65536 + bh] = c2;
        P.hst[(1 - p) * POFF + ld * 65536 + bh] = (_Float16)h2;
        if (yout) yout[(long)m * 1024 + ydir * 512 + jh] = (_Float16)h2;
      }
    }
  }
}

__launch_bounds__(256, 2)
__global__ void seq_persist(PP P) {
  cg::grid_group grid = cg::this_grid();
  const int bid = blockIdx.x;
  const int tid = threadIdx.x;
  const int wave = tid >> 6, lane = tid & 63;
  __shared__ _Float16 WL[24576];   // 48 KB: up to K=1536 x 16 cols

  // ================= Encoder (512 blocks = 2 dir x 2 mgroup x 128 ntile) ====
  {
    const int dir = bid >> 8;
    const int r = bid & 255;
    const int mg = r >> 7, nidx = r & 127;
    const int jh0 = nidx * 4;
    const int mbase = mg * 64 + wave * 16;

    // ---- phase 0: encoder layer 0 ----
    stage_w(WL, P.ew0 + (long)dir * G4 * C_IN, C_IN, C_IN, 0, jh0, tid);
    stage_w(WL, P.ewh + (long)dir * G4 * H_SZ, H_SZ, H_SZ, C_IN, jh0, tid);
    __syncthreads();
    for (int s = 0; s < T_LEN; ++s) {
      const int p = s & 1;
      const int td = dir ? (T_LEN - 1 - s) : s;
      do_step<1>(WL,
                 P.xT + (long)td * (B_SZ * C_IN), C_IN, C_IN / 32,
                 P.hst + p * POFF + dir * 65536, H_SZ, H_SZ / 32,
                 nullptr, 0, 0,
                 mbase, jh0, dir, dir, p,
                 P.y0 + (long)td * (B_SZ * 1024), dir, P, lane);
      grid.sync();
    }

    // ---- phase 1: encoder layer 1 (finals only) ----
    stage_w(WL, P.ewr + (long)dir * G4 * 1024, 1024, 1024, 0, jh0, tid);
    stage_w(WL, P.ewh + (long)(2 + dir) * G4 * H_SZ, H_SZ, H_SZ, 1024, jh0, tid);
    __syncthreads();
    for (int s = 0; s < T_LEN; ++s) {
      const int p = s & 1;
      const int td = dir ? (T_LEN - 1 - s) : s;
      do_step<1>(WL,
                 P.y0 + (long)td * (B_SZ * 1024), 1024, 1024 / 32,
                 P.hst + p * POFF + (2 + dir) * 65536, H_SZ, H_SZ / 32,
                 nullptr, 0, 0,
                 mbase, jh0, 2 + dir, 2 + dir, p,
                 nullptr, 0, P, lane);
      grid.sync();
    }
  }

  // ================= Decoder (4 jobs x 128 ntiles, l0/l1 1-step skew) =======
  {
    const int q = bid >> 7;            // 0=l0f 1=l0b 2=l1f 3=l1b
    const int layer = q >> 1, dir = q & 1;
    const int r = bid & 127;
    const int jh0 = r * 4;
    const int mbase = wave * 32;
    const int slot = 4 + layer * 2 + dir;
    const int ld = layer * 2 + dir;

    if (layer == 0) {
      stage_w(WL, P.dw0 + (long)dir * G4 * C_IN, C_IN, C_IN, 0, jh0, tid);
      stage_w(WL, P.dwh + (long)dir * G4 * H_SZ, H_SZ, H_SZ, C_IN, jh0, tid);
    } else {
      stage_w(WL, P.dwr + (long)dir * G4 * 1024, 1024, 1024, 0, jh0, tid);
      stage_w(WL, P.dwh + (long)ld * G4 * H_SZ, H_SZ, H_SZ, 1024, jh0, tid);
    }
    __syncthreads();

    for (int s = 0; s <= T_LEN; ++s) {
      const int p = s & 1;
      if (layer == 1 && s == 0) {
        // seed l1 state into parity 1 (step s=1 reads parity 1)
        for (int i = tid; i < 512; i += 256) {
          const int idx = r * 512 + i;
          P.hst[POFF + ld * 65536 + idx] = P.hst[ld * 65536 + idx];
          P.cst[POFF + ld * 65536 + idx] = P.cst[ld * 65536 + idx];
        }
      } else if (layer == 0 && s < T_LEN) {
        do_step<2>(WL,
                   P.xT + (long)s * (B_SZ * C_IN), C_IN, C_IN / 32,
                   P.hst + p * POFF + dir * 65536, H_SZ, H_SZ / 32,
                   nullptr, 0, 0,
                   mbase, jh0, slot, ld, p, nullptr, 0, P, lane);
      } else if (layer == 1 && s >= 1) {
        do_step<2>(WL,
                   P.hst + p * POFF + 0 * 65536, H_SZ, 16,
                   P.hst + p * POFF + 1 * 65536, H_SZ, 16,
                   P.hst + p * POFF + ld * 65536, H_SZ, 16,
                   mbase, jh0, slot, ld, p, nullptr, 0, P, lane);
      }
      grid.sync();
    }
  }
}

// ---------------------------------------------------------------------------
__global__ void f2h(const float* __restrict__ src, _Float16* __restrict__ dst, long n) {
  for (long i = blockIdx.x * 256L + threadIdx.x; i < n; i += (long)gridDim.x * 256)
    dst[i] = (_Float16)src[i];
}

__global__ void x_transpose(const float* __restrict__ x, _Float16* __restrict__ xT) {
  const int t = blockIdx.x, b = blockIdx.y, c = threadIdx.x;
  xT[((long)t * B_SZ + b) * C_IN + c] = (_Float16)x[((long)b * T_LEN + t) * C_IN + c];
}

__global__ void bias_combine(const float* __restrict__ e_bih, const float* __restrict__ e_bhh,
                             const float* __restrict__ d_bih, const float* __restrict__ d_bhh,
                             float* __restrict__ bcomb) {
  const int i = blockIdx.x * 256 + threadIdx.x;  // 0..16383
  const int slot = i >> 11;
  const int j = i & 2047;
  float v;
  if (slot < 4) v = e_bih[slot * 2048 + j] + e_bhh[slot * 2048 + j];
  else          v = d_bih[(slot - 4) * 2048 + j] + d_bhh[(slot - 4) * 2048 + j];
  bcomb[i] = v;
}

__global__ void final_linear(const _Float16* __restrict__ hf, const _Float16* __restrict__ hb,
                             const float* __restrict__ lin_w, const float* __restrict__ lb,
                             float* __restrict__ out) {
  const int tid = threadIdx.x;
  const int o = tid & 127;
  const int b = blockIdx.x * 2 + (tid >> 7);
  float acc = 0.f;
  const _Float16* h1 = hf + (long)b * H_SZ;
  const _Float16* h2 = hb + (long)b * H_SZ;
  const float* w = lin_w + (long)o * 1024;
  for (int k = 0; k < H_SZ; ++k) acc += (float)h1[k] * w[k];
  for (int k = 0; k < H_SZ; ++k) acc += (float)h2[k] * w[H_SZ + k];
  out[(long)b * 128 + o] = acc + lb[o];
}

// ---------------------------------------------------------------------------
extern "C" void kernel_launch(void* const* d_in, const int* in_sizes, int n_in,
                              void* d_out, int out_size, void* d_ws, size_t ws_size,
                              hipStream_t stream) {
  (void)in_sizes; (void)n_in;
  const float* x      = (const float*)d_in[0];
  const float* h0     = (const float*)d_in[1];
  const float* c0     = (const float*)d_in[2];
  const float* e_wih0 = (const float*)d_in[3];
  const float* e_wihr = (const float*)d_in[4];
  const float* e_whh  = (const float*)d_in[5];
  const float* e_bih  = (const float*)d_in[6];
  const float* e_bhh  = (const float*)d_in[7];
  const float* dw_ih0 = (const float*)d_in[8];
  const float* dw_ihr = (const float*)d_in[9];
  const float* dw_hh  = (const float*)d_in[10];
  const float* db_ih  = (const float*)d_in[11];
  const float* db_hh  = (const float*)d_in[12];
  const float* lin_w  = (const float*)d_in[13];
  const float* lin_b  = (const float*)d_in[14];
  float* out = (float*)d_out;

  char* wsb = (char*)d_ws;
  size_t off = 0;
  auto carve = [&](size_t bytes) -> void* {
    void* pp = wsb + off;
    off += (bytes + 255) & ~(size_t)255;
    return pp;
  };
  _Float16* xT  = (_Float16*)carve((size_t)T_LEN * B_SZ * C_IN * 2);
  _Float16* ew0 = (_Float16*)carve(2L * G4 * C_IN * 2);
  _Float16* ewr = (_Float16*)carve(2L * G4 * 1024 * 2);
  _Float16* ewh = (_Float16*)carve(4L * G4 * H_SZ * 2);
  _Float16* dw0 = (_Float16*)carve(2L * G4 * C_IN * 2);
  _Float16* dwr = (_Float16*)carve(2L * G4 * 1024 * 2);
  _Float16* dwh = (_Float16*)carve(4L * G4 * H_SZ * 2);
  _Float16* y0  = (_Float16*)carve((size_t)T_LEN * B_SZ * 1024 * 2);
  float* bcomb  = (float*)carve(8L * G4 * 4);
  _Float16* hst = (_Float16*)carve(2L * POFF * 2);
  float* cst    = (float*)carve(2L * POFF * 4);

  if (off > ws_size) {  // diagnostic: absmax would equal ref absmax (~0.465)
    hipMemsetAsync(d_out, 0, (size_t)out_size * 4, stream);
    return;
  }

  // ---- prep ----
  x_transpose<<<dim3(T_LEN, B_SZ), C_IN, 0, stream>>>(x, xT);
  f2h<<<64,  256, 0, stream>>>(e_wih0, ew0, 2L * G4 * C_IN);
  f2h<<<256, 256, 0, stream>>>(e_wihr, ewr, 2L * G4 * 1024);
  f2h<<<256, 256, 0, stream>>>(e_whh,  ewh, 4L * G4 * H_SZ);
  f2h<<<64,  256, 0, stream>>>(dw_ih0, dw0, 2L * G4 * C_IN);
  f2h<<<256, 256, 0, stream>>>(dw_ihr, dwr, 2L * G4 * 1024);
  f2h<<<256, 256, 0, stream>>>(dw_hh,  dwh, 4L * G4 * H_SZ);
  f2h<<<64,  256, 0, stream>>>(h0,     hst, (long)POFF);      // parity 0
  bias_combine<<<64, 256, 0, stream>>>(e_bih, e_bhh, db_ih, db_hh, bcomb);
  hipMemcpyAsync(cst, c0, (size_t)POFF * 4, hipMemcpyDeviceToDevice, stream);

  // ---- persistent cooperative kernel: all 1537 sequential steps ----
  PP P{ xT, ew0, ewr, ewh, dw0, dwr, dwh, bcomb, y0, hst, cst };
  void* kargs[] = { &P };
  hipLaunchCooperativeKernel((void*)seq_persist, dim3(512), dim3(256), kargs, 0, stream);

  // ---- final linear on decoder l1 output at t=511 (parity 1, ld 2/3) ----
  final_linear<<<64, 256, 0, stream>>>(hst + POFF + 2 * 65536, hst + POFF + 3 * 65536,
                                       lin_w, lin_b, out);
}

// Round 5
// 97222.528 us; speedup vs baseline: 1.1578x; 1.1578x over previous
//
#include <hip/hip_runtime.h>
#include <hip/hip_cooperative_groups.h>

namespace cg = cooperative_groups;

#define T_LEN 512
#define B_SZ  128
#define C_IN  128
#define H_SZ  512
#define G4    2048
#define HSLICE 65536   // halves per hF (ld) slice: 16q*8mt*64l*8e
#define HPAR  262144   // halves per parity (4 slices)
#define XFT   16384    // halves per xF[t]
#define Y0T   131072   // halves per y0F[t]

typedef _Float16 half8 __attribute__((ext_vector_type(8)));
typedef float    float4v __attribute__((ext_vector_type(4)));

struct PP {
  const _Float16* xF;                          // [T] frag-layout x
  const _Float16 *ew0, *ewr, *ewh, *dw0, *dwr, *dwh;  // j-major fp16
  const float* bcomb;                          // [8][2048]
  _Float16* y0F;                               // [T] frag-layout enc-l0 out
  _Float16* hst;                               // [2][4] frag-layout h
  float*    cst;                               // [4][B][H] plain
};

// frag layout: element (m,k) at (k>>5)*4096 + (m>>4)*512 + ((k>>3)&3)*128 + (m&15)*8 + (k&7)
__device__ __forceinline__ long fragAddr(int m, int k) {
  return (long)(k >> 5) * 4096 + (m >> 4) * 512 + ((k >> 3) & 3) * 128 + (m & 15) * 8 + (k & 7);
}

// Stage 16 gate-cols (jh0..jh0+3 x 4 gates) of [W1;W2] (k-concat) into LDS,
// linear per-lane layout: WF[(q*64 + lane)*8] = W[j(lane&15)][q*32+(lane>>4)*8 ..+8]
__device__ __forceinline__ void stage_w2(_Float16* WF,
    const _Float16* W1, long st1, int K1,
    const _Float16* W2, long st2, int K2, int jh0, int tid) {
  const int n8 = ((K1 + K2) >> 5) * 64;
  for (int idx = tid; idx < n8; idx += 256) {
    const int q = idx >> 6, l = idx & 63;
    const int c = l & 15, qd = l >> 4;
    const int j = (c >> 2) * 512 + jh0 + (c & 3);
    const int k = q * 32 + qd * 8;
    const _Float16* src = (k < K1) ? (W1 + (long)j * st1 + k)
                                   : (W2 + (long)j * st2 + (k - K1));
    *(half8*)(WF + (long)idx * 8) = *(const half8*)src;
  }
}

// One LSTM step: this wave computes MTS m-tiles x 16 gate-cols, B from LDS
// (conflict-free), A from frag-layout global (coalesced 1KB/wave), c in regs.
template <int MTS>
__device__ __forceinline__ void do_step(const _Float16* WF,
    const _Float16* A0, int q0, const _Float16* A1, int q1,
    const _Float16* A2, int q2,
    int mt0, int jh0, int ld, int p,
    float* c_reg, const float* b4,
    _Float16* yb, int ydir, const PP& P, int lane) {
  const int quad = lane >> 4;
  float4v acc[MTS][2];
  #pragma unroll
  for (int mt = 0; mt < MTS; ++mt) {
    acc[mt][0] = {0.f, 0.f, 0.f, 0.f};
    acc[mt][1] = {0.f, 0.f, 0.f, 0.f};
  }
  const _Float16* wl = WF + lane * 8;
  const _Float16* segA[3] = {A0, A1, A2};
  const int segQ[3] = {q0, q1, q2};
  int kq = 0;
  for (int sg = 0; sg < 3; ++sg) {
    const int nq = segQ[sg];
    if (nq == 0) break;
    const _Float16* ab = segA[sg] + (long)mt0 * 512 + lane * 8;
    #pragma unroll 4
    for (int qq = 0; qq < nq; ++qq) {
      const half8 bf = *(const half8*)(wl + (long)(kq + qq) * 512);
      #pragma unroll
      for (int mt = 0; mt < MTS; ++mt) {
        const half8 af = *(const half8*)(ab + (long)mt * 512 + (long)qq * 4096);
        acc[mt][(kq + qq) & 1] =
            __builtin_amdgcn_mfma_f32_16x16x32_f16(af, bf, acc[mt][(kq + qq) & 1], 0, 0, 0);
      }
    }
    kq += nq;
  }
  // epilogue: C-frag col=lane&15 (gate*4+jl), row=quad*4+r
  const int jl = lane & 3;
  const int jh = jh0 + jl;
  const bool wr = (lane & 12) == 0;
  const int sbase = (lane & 48) | jl;
  #pragma unroll
  for (int mt = 0; mt < MTS; ++mt) {
    #pragma unroll
    for (int r = 0; r < 4; ++r) {
      const float v = acc[mt][0][r] + acc[mt][1][r];
      const float iv = __shfl(v, sbase);
      const float fv = __shfl(v, sbase | 4);
      const float gv = __shfl(v, sbase | 8);
      const float ov = __shfl(v, sbase | 12);
      if (wr) {
        const int m = (mt0 + mt) * 16 + quad * 4 + r;
        const float ig = iv + b4[0], fg = fv + b4[1], gg = gv + b4[2], og = ov + b4[3];
        const float si = 1.f / (1.f + __expf(-ig));
        const float sf = 1.f / (1.f + __expf(-fg));
        const float so = 1.f / (1.f + __expf(-og));
        const float eg = __expf(2.f * gg);
        const float tg = (eg - 1.f) / (eg + 1.f);
        const float c2 = sf * c_reg[mt * 4 + r] + si * tg;
        c_reg[mt * 4 + r] = c2;
        const float ec = __expf(2.f * c2);
        const float h2 = so * (ec - 1.f) / (ec + 1.f);
        P.hst[(long)(1 - p) * HPAR + (long)ld * HSLICE + fragAddr(m, jh)] = (_Float16)h2;
        if (yb) yb[fragAddr(m, ydir * 512 + jh)] = (_Float16)h2;
      }
    }
  }
}

__launch_bounds__(256, 2)
__global__ void seq_persist(PP P) {
  cg::grid_group grid = cg::this_grid();
  const int bid = blockIdx.x, tid = threadIdx.x;
  const int wave = tid >> 6, lane = tid & 63;
  const int quad = lane >> 4;
  __shared__ _Float16 WF[24576];   // 48 KB

  // ================= Encoder: 2 dirs x 2 mgroups x 128 jh-tiles =============
  {
    const int dir = bid >> 8;
    const int mg = (bid >> 7) & 1;
    const int rsw = bid & 127;
    const int nidx = (rsw & 7) * 16 + (rsw >> 3);   // XCD-contiguous jh
    const int jh0 = nidx * 4;
    const int jh = jh0 + (lane & 3);
    const int mt0 = mg * 4 + wave;                  // MTS=1

    for (int ph = 0; ph < 2; ++ph) {
      const int ld = ph * 2 + dir;
      if (ph == 0)
        stage_w2(WF, P.ew0 + (long)dir * G4 * C_IN, C_IN, C_IN,
                     P.ewh + (long)dir * G4 * H_SZ, H_SZ, H_SZ, jh0, tid);
      else
        stage_w2(WF, P.ewr + (long)dir * G4 * 1024, 1024, 1024,
                     P.ewh + (long)(2 + dir) * G4 * H_SZ, H_SZ, H_SZ, jh0, tid);
      __syncthreads();
      float b4[4], c_reg[4];
      #pragma unroll
      for (int g = 0; g < 4; ++g) b4[g] = P.bcomb[(long)ld * G4 + g * 512 + jh];
      #pragma unroll
      for (int r = 0; r < 4; ++r)
        c_reg[r] = P.cst[(long)ld * HSLICE + (long)(mt0 * 16 + quad * 4 + r) * H_SZ + jh];

      for (int s = 0; s < T_LEN; ++s) {
        const int p = s & 1;
        const int td = dir ? (T_LEN - 1 - s) : s;
        if (ph == 0)
          do_step<1>(WF, P.xF + (long)td * XFT, 4,
                     P.hst + (long)p * HPAR + (long)dir * HSLICE, 16, nullptr, 0,
                     mt0, jh0, ld, p, c_reg, b4,
                     P.y0F + (long)td * Y0T, dir, P, lane);
        else
          do_step<1>(WF, P.y0F + (long)td * Y0T, 32,
                     P.hst + (long)p * HPAR + (long)ld * HSLICE, 16, nullptr, 0,
                     mt0, jh0, ld, p, c_reg, b4, nullptr, 0, P, lane);
        grid.sync();
      }
      if ((lane & 12) == 0) {
        #pragma unroll
        for (int r = 0; r < 4; ++r)
          P.cst[(long)ld * HSLICE + (long)(mt0 * 16 + quad * 4 + r) * H_SZ + jh] = c_reg[r];
      }
    }
    grid.sync();   // cst[2|3] visible before decoder l1 loads them
  }

  // ================= Decoder: 4 jobs x 128 jh-tiles, l0/l1 1-step skew ======
  {
    const int q = bid >> 7;              // 0=l0f 1=l0b 2=l1f 3=l1b
    const int layer = q >> 1, dir = q & 1;
    const int rsw = bid & 127;
    const int nidx = (rsw & 7) * 16 + (rsw >> 3);
    const int jh0 = nidx * 4;
    const int jh = jh0 + (lane & 3);
    const int mt0 = wave * 2;            // MTS=2
    const int slot = 4 + layer * 2 + dir;
    const int ld = layer * 2 + dir;

    if (layer == 0)
      stage_w2(WF, P.dw0 + (long)dir * G4 * C_IN, C_IN, C_IN,
                   P.dwh + (long)dir * G4 * H_SZ, H_SZ, H_SZ, jh0, tid);
    else
      stage_w2(WF, P.dwr + (long)dir * G4 * 1024, 1024, 1024,
                   P.dwh + (long)(2 + dir) * G4 * H_SZ, H_SZ, H_SZ, jh0, tid);
    __syncthreads();
    float b4[4], c_reg[8];
    #pragma unroll
    for (int g = 0; g < 4; ++g) b4[g] = P.bcomb[(long)slot * G4 + g * 512 + jh];
    #pragma unroll
    for (int mt = 0; mt < 2; ++mt)
      #pragma unroll
      for (int r = 0; r < 4; ++r)
        c_reg[mt * 4 + r] =
            P.cst[(long)ld * HSLICE + (long)((mt0 + mt) * 16 + quad * 4 + r) * H_SZ + jh];

    for (int s = 0; s <= T_LEN; ++s) {
      const int p = s & 1;
      if (layer == 1 && s == 0) {
        // seed l1 h into parity 1 (step s=1 reads parity 1)
        if (tid < 64) {
          const long off = (long)(2 + dir) * HSLICE + ((long)rsw * 64 + tid) * 8;
          *(half8*)(P.hst + HPAR + off) = *(const half8*)(P.hst + off);
        }
      } else if (layer == 0 && s < T_LEN) {
        do_step<2>(WF, P.xF + (long)s * XFT, 4,
                   P.hst + (long)p * HPAR + (long)dir * HSLICE, 16, nullptr, 0,
                   mt0, jh0, ld, p, c_reg, b4, nullptr, 0, P, lane);
      } else if (layer == 1 && s >= 1) {
        do_step<2>(WF, P.hst + (long)p * HPAR + 0 * HSLICE, 16,
                       P.hst + (long)p * HPAR + 1 * HSLICE, 16,
                       P.hst + (long)p * HPAR + (long)(2 + dir) * HSLICE, 16,
                   mt0, jh0, ld, p, c_reg, b4, nullptr, 0, P, lane);
      }
      grid.sync();
    }
  }
}

// ---------------------------------------------------------------------------
__global__ void f2h(const float* __restrict__ src, _Float16* __restrict__ dst, long n) {
  for (long i = blockIdx.x * 256L + threadIdx.x; i < n; i += (long)gridDim.x * 256)
    dst[i] = (_Float16)src[i];
}

__global__ void x_to_frag(const float* __restrict__ x, _Float16* __restrict__ xF) {
  const int t = blockIdx.x, b = blockIdx.y, c = threadIdx.x;
  xF[(long)t * XFT + fragAddr(b, c)] = (_Float16)x[((long)b * T_LEN + t) * C_IN + c];
}

__global__ void h0_to_frag(const float* __restrict__ h0, _Float16* __restrict__ hstF) {
  const long i = blockIdx.x * 256L + threadIdx.x;   // over 4*128*512
  const int ld = (int)(i >> 16);
  const int b = (int)((i >> 9) & 127);
  const int k = (int)(i & 511);
  hstF[(long)ld * HSLICE + fragAddr(b, k)] = (_Float16)h0[i];
}

__global__ void bias_combine(const float* __restrict__ e_bih, const float* __restrict__ e_bhh,
                             const float* __restrict__ d_bih, const float* __restrict__ d_bhh,
                             float* __restrict__ bcomb) {
  const int i = blockIdx.x * 256 + threadIdx.x;  // 0..16383
  const int slot = i >> 11;
  const int j = i & 2047;
  float v;
  if (slot < 4) v = e_bih[slot * 2048 + j] + e_bhh[slot * 2048 + j];
  else          v = d_bih[(slot - 4) * 2048 + j] + d_bhh[(slot - 4) * 2048 + j];
  bcomb[i] = v;
}

__global__ void final_linear(const _Float16* __restrict__ hF,  // hst + HPAR (parity 1)
                             const float* __restrict__ lin_w, const float* __restrict__ lb,
                             float* __restrict__ out) {
  const int tid = threadIdx.x;
  const int o = tid & 127;
  const int b = blockIdx.x * 2 + (tid >> 7);
  const float* w = lin_w + (long)o * 1024;
  float acc = 0.f;
  for (int k = 0; k < H_SZ; ++k) acc += (float)hF[2L * HSLICE + fragAddr(b, k)] * w[k];
  for (int k = 0; k < H_SZ; ++k) acc += (float)hF[3L * HSLICE + fragAddr(b, k)] * w[H_SZ + k];
  out[(long)b * 128 + o] = acc + lb[o];
}

// ---------------------------------------------------------------------------
extern "C" void kernel_launch(void* const* d_in, const int* in_sizes, int n_in,
                              void* d_out, int out_size, void* d_ws, size_t ws_size,
                              hipStream_t stream) {
  (void)in_sizes; (void)n_in;
  const float* x      = (const float*)d_in[0];
  const float* h0     = (const float*)d_in[1];
  const float* c0     = (const float*)d_in[2];
  const float* e_wih0 = (const float*)d_in[3];
  const float* e_wihr = (const float*)d_in[4];
  const float* e_whh  = (const float*)d_in[5];
  const float* e_bih  = (const float*)d_in[6];
  const float* e_bhh  = (const float*)d_in[7];
  const float* dw_ih0 = (const float*)d_in[8];
  const float* dw_ihr = (const float*)d_in[9];
  const float* dw_hh  = (const float*)d_in[10];
  const float* db_ih  = (const float*)d_in[11];
  const float* db_hh  = (const float*)d_in[12];
  const float* lin_w  = (const float*)d_in[13];
  const float* lin_b  = (const float*)d_in[14];
  float* out = (float*)d_out;

  char* wsb = (char*)d_ws;
  size_t off = 0;
  auto carve = [&](size_t bytes) -> void* {
    void* pp = wsb + off;
    off += (bytes + 255) & ~(size_t)255;
    return pp;
  };
  _Float16* xF  = (_Float16*)carve((size_t)T_LEN * XFT * 2);
  _Float16* ew0 = (_Float16*)carve(2L * G4 * C_IN * 2);
  _Float16* ewr = (_Float16*)carve(2L * G4 * 1024 * 2);
  _Float16* ewh = (_Float16*)carve(4L * G4 * H_SZ * 2);
  _Float16* dw0 = (_Float16*)carve(2L * G4 * C_IN * 2);
  _Float16* dwr = (_Float16*)carve(2L * G4 * 1024 * 2);
  _Float16* dwh = (_Float16*)carve(4L * G4 * H_SZ * 2);
  _Float16* y0F = (_Float16*)carve((size_t)T_LEN * Y0T * 2);   // 128 MB
  float* bcomb  = (float*)carve(8L * G4 * 4);
  _Float16* hst = (_Float16*)carve(2L * HPAR * 2);
  float* cst    = (float*)carve(4L * HSLICE * 4);

  if (off > ws_size) {   // diagnostic: output stays zero -> absmax == ref absmax
    hipMemsetAsync(d_out, 0, (size_t)out_size * 4, stream);
    return;
  }

  // ---- prep ----
  x_to_frag<<<dim3(T_LEN, B_SZ), C_IN, 0, stream>>>(x, xF);
  f2h<<<64,  256, 0, stream>>>(e_wih0, ew0, 2L * G4 * C_IN);
  f2h<<<256, 256, 0, stream>>>(e_wihr, ewr, 2L * G4 * 1024);
  f2h<<<256, 256, 0, stream>>>(e_whh,  ewh, 4L * G4 * H_SZ);
  f2h<<<64,  256, 0, stream>>>(dw_ih0, dw0, 2L * G4 * C_IN);
  f2h<<<256, 256, 0, stream>>>(dw_ihr, dwr, 2L * G4 * 1024);
  f2h<<<256, 256, 0, stream>>>(dw_hh,  dwh, 4L * G4 * H_SZ);
  h0_to_frag<<<1024, 256, 0, stream>>>(h0, hst);               // parity 0
  bias_combine<<<64, 256, 0, stream>>>(e_bih, e_bhh, db_ih, db_hh, bcomb);
  hipMemcpyAsync(cst, c0, 4L * HSLICE * 4, hipMemcpyDeviceToDevice, stream);

  // ---- persistent cooperative kernel: all 1537 sequential steps ----
  PP P{ xF, ew0, ewr, ewh, dw0, dwr, dwh, bcomb, y0F, hst, cst };
  void* kargs[] = { &P };
  hipLaunchCooperativeKernel((void*)seq_persist, dim3(512), dim3(256), kargs, 0, stream);

  // ---- final linear on decoder l1 t=511 output (parity 1, ld 2/3) ----
  final_linear<<<64, 256, 0, stream>>>(hst + HPAR, lin_w, lin_b, out);
}

// Round 6
// 19367.877 us; speedup vs baseline: 5.8122x; 5.0198x over previous
//
#include <hip/hip_runtime.h>
#include <hip/hip_cooperative_groups.h>

#define T_LEN 512
#define B_SZ  128
#define C_IN  128
#define H_SZ  512
#define G4    2048
#define HSLICE 65536   // halves per hF (ld) slice
#define HPAR  262144   // halves per parity (4 slices)
#define XFT   16384    // halves per xF[t]
#define Y0T   131072   // halves per y0F[t]

typedef _Float16 half8 __attribute__((ext_vector_type(8)));
typedef float    float4v __attribute__((ext_vector_type(4)));

#define SCOPE __HIP_MEMORY_SCOPE_AGENT

// Coherent (L2-bypass, L3-backed) access helpers — relaxed: no cache flushes.
__device__ __forceinline__ half8 ld_h8c(const _Float16* p) {
  const unsigned long long* q = (const unsigned long long*)p;
  union { unsigned long long u[2]; half8 h; } v;
  v.u[0] = __hip_atomic_load(q,     __ATOMIC_RELAXED, SCOPE);
  v.u[1] = __hip_atomic_load(q + 1, __ATOMIC_RELAXED, SCOPE);
  return v.h;
}
__device__ __forceinline__ void st_h2c(_Float16* p, float x) {
  union { _Float16 f; unsigned short s; } v; v.f = (_Float16)x;
  __hip_atomic_store((unsigned short*)p, v.s, __ATOMIC_RELAXED, SCOPE);
}
__device__ __forceinline__ float ld_f32c(const float* p) {
  return __hip_atomic_load(p, __ATOMIC_RELAXED, SCOPE);
}
__device__ __forceinline__ void st_f32c(float* p, float x) {
  __hip_atomic_store(p, x, __ATOMIC_RELAXED, SCOPE);
}

struct PP {
  const _Float16* xF;
  const _Float16 *ew0, *ewr, *ewh, *dw0, *dwr, *dwh;
  const float* bcomb;
  _Float16* y0F;
  _Float16* hst;
  float*    cst;
  unsigned int* bar;   // [8*32] leaf cnts, [256] root, [257] gen
};

// Custom grid barrier: 2-level monotonic counters, relaxed agent atomics only.
// __syncthreads drains each wave's outstanding stores (vmcnt0) = release;
// in-order issue after spin + compiler barrier = acquire. No L2 flush.
__device__ __forceinline__ void gbar(unsigned int* bar, int bid, int& cnt) {
  __syncthreads();
  ++cnt;
  if (threadIdx.x == 0) {
    const unsigned target = (unsigned)cnt;
    unsigned int* leaf = bar + (bid & 7) * 32;
    unsigned old = __hip_atomic_fetch_add(leaf, 1u, __ATOMIC_RELAXED, SCOPE);
    if (old + 1 == 64u * target) {
      unsigned ro = __hip_atomic_fetch_add(bar + 256, 1u, __ATOMIC_RELAXED, SCOPE);
      if (ro + 1 == 8u * target)
        __hip_atomic_store(bar + 257, target, __ATOMIC_RELAXED, SCOPE);
    }
    while (__hip_atomic_load(bar + 257, __ATOMIC_RELAXED, SCOPE) < target)
      __builtin_amdgcn_s_sleep(2);
  }
  __syncthreads();
  asm volatile("" ::: "memory");
}

// frag layout: element (m,k) at (k>>5)*4096 + (m>>4)*512 + ((k>>3)&3)*128 + (m&15)*8 + (k&7)
__device__ __forceinline__ long fragAddr(int m, int k) {
  return (long)(k >> 5) * 4096 + (m >> 4) * 512 + ((k >> 3) & 3) * 128 + (m & 15) * 8 + (k & 7);
}

// Stage 16 gate-cols of [W1;W2] (k-concat) into LDS (normal cached loads).
__device__ __forceinline__ void stage_w2(_Float16* WF,
    const _Float16* W1, long st1, int K1,
    const _Float16* W2, long st2, int K2, int jh0, int tid) {
  const int n8 = ((K1 + K2) >> 5) * 64;
  for (int idx = tid; idx < n8; idx += 256) {
    const int q = idx >> 6, l = idx & 63;
    const int c = l & 15, qd = l >> 4;
    const int j = (c >> 2) * 512 + jh0 + (c & 3);
    const int k = q * 32 + qd * 8;
    const _Float16* src = (k < K1) ? (W1 + (long)j * st1 + k)
                                   : (W2 + (long)j * st2 + (k - K1));
    *(half8*)(WF + (long)idx * 8) = *(const half8*)src;
  }
}

// One LSTM step: B from LDS (conflict-free), A via coherent L3 loads, c in regs.
template <int MTS>
__device__ __forceinline__ void do_step(const _Float16* WF,
    const _Float16* A0, int q0, const _Float16* A1, int q1,
    const _Float16* A2, int q2,
    int mt0, int jh0, int ld, int p,
    float* c_reg, const float* b4,
    _Float16* yb, int ydir, const PP& P, int lane) {
  const int quad = lane >> 4;
  float4v acc[MTS][2];
  #pragma unroll
  for (int mt = 0; mt < MTS; ++mt) {
    acc[mt][0] = {0.f, 0.f, 0.f, 0.f};
    acc[mt][1] = {0.f, 0.f, 0.f, 0.f};
  }
  const _Float16* wl = WF + lane * 8;
  const _Float16* segA[3] = {A0, A1, A2};
  const int segQ[3] = {q0, q1, q2};
  int kq = 0;
  for (int sg = 0; sg < 3; ++sg) {
    const int nq = segQ[sg];
    if (nq == 0) break;
    const _Float16* ab = segA[sg] + (long)mt0 * 512 + lane * 8;
    #pragma unroll 4
    for (int qq = 0; qq < nq; ++qq) {
      const half8 bf = *(const half8*)(wl + (long)(kq + qq) * 512);
      #pragma unroll
      for (int mt = 0; mt < MTS; ++mt) {
        const half8 af = ld_h8c(ab + (long)mt * 512 + (long)qq * 4096);
        acc[mt][(kq + qq) & 1] =
            __builtin_amdgcn_mfma_f32_16x16x32_f16(af, bf, acc[mt][(kq + qq) & 1], 0, 0, 0);
      }
    }
    kq += nq;
  }
  // epilogue: C-frag col=lane&15 (gate*4+jl), row=quad*4+r
  const int jl = lane & 3;
  const int jh = jh0 + jl;
  const bool wr = (lane & 12) == 0;
  const int sbase = (lane & 48) | jl;
  #pragma unroll
  for (int mt = 0; mt < MTS; ++mt) {
    #pragma unroll
    for (int r = 0; r < 4; ++r) {
      const float v = acc[mt][0][r] + acc[mt][1][r];
      const float iv = __shfl(v, sbase);
      const float fv = __shfl(v, sbase | 4);
      const float gv = __shfl(v, sbase | 8);
      const float ov = __shfl(v, sbase | 12);
      if (wr) {
        const int m = (mt0 + mt) * 16 + quad * 4 + r;
        const float ig = iv + b4[0], fg = fv + b4[1], gg = gv + b4[2], og = ov + b4[3];
        const float si = 1.f / (1.f + __expf(-ig));
        const float sf = 1.f / (1.f + __expf(-fg));
        const float so = 1.f / (1.f + __expf(-og));
        const float eg = __expf(2.f * gg);
        const float tg = (eg - 1.f) / (eg + 1.f);
        const float c2 = sf * c_reg[mt * 4 + r] + si * tg;
        c_reg[mt * 4 + r] = c2;
        const float ec = __expf(2.f * c2);
        const float h2 = so * (ec - 1.f) / (ec + 1.f);
        st_h2c(&P.hst[(long)(1 - p) * HPAR + (long)ld * HSLICE + fragAddr(m, jh)], h2);
        if (yb) st_h2c(&yb[fragAddr(m, ydir * 512 + jh)], h2);
      }
    }
  }
}

__launch_bounds__(256, 2)
__global__ void seq_persist(PP P) {
  const int bid = blockIdx.x, tid = threadIdx.x;
  const int wave = tid >> 6, lane = tid & 63;
  const int quad = lane >> 4;
  __shared__ _Float16 WF[24576];   // 48 KB
  int bcnt = 0;

  // ================= Encoder: 2 dirs x 2 mgroups x 128 jh-tiles =============
  {
    const int dir = bid >> 8;
    const int mg = (bid >> 7) & 1;
    const int rsw = bid & 127;
    const int nidx = (rsw & 7) * 16 + (rsw >> 3);   // XCD-contiguous jh
    const int jh0 = nidx * 4;
    const int jh = jh0 + (lane & 3);
    const int mt0 = mg * 4 + wave;                  // MTS=1

    for (int ph = 0; ph < 2; ++ph) {
      const int ld = ph * 2 + dir;
      if (ph == 0)
        stage_w2(WF, P.ew0 + (long)dir * G4 * C_IN, C_IN, C_IN,
                     P.ewh + (long)dir * G4 * H_SZ, H_SZ, H_SZ, jh0, tid);
      else
        stage_w2(WF, P.ewr + (long)dir * G4 * 1024, 1024, 1024,
                     P.ewh + (long)(2 + dir) * G4 * H_SZ, H_SZ, H_SZ, jh0, tid);
      __syncthreads();
      float b4[4], c_reg[4];
      #pragma unroll
      for (int g = 0; g < 4; ++g) b4[g] = P.bcomb[(long)ld * G4 + g * 512 + jh];
      #pragma unroll
      for (int r = 0; r < 4; ++r)
        c_reg[r] = ld_f32c(&P.cst[(long)ld * HSLICE + (long)(mt0 * 16 + quad * 4 + r) * H_SZ + jh]);

      for (int s = 0; s < T_LEN; ++s) {
        const int p = s & 1;
        const int td = dir ? (T_LEN - 1 - s) : s;
        if (ph == 0)
          do_step<1>(WF, P.xF + (long)td * XFT, 4,
                     P.hst + (long)p * HPAR + (long)dir * HSLICE, 16, nullptr, 0,
                     mt0, jh0, ld, p, c_reg, b4,
                     P.y0F + (long)td * Y0T, dir, P, lane);
        else
          do_step<1>(WF, P.y0F + (long)td * Y0T, 32,
                     P.hst + (long)p * HPAR + (long)ld * HSLICE, 16, nullptr, 0,
                     mt0, jh0, ld, p, c_reg, b4, nullptr, 0, P, lane);
        gbar(P.bar, bid, bcnt);
      }
      if ((lane & 12) == 0) {
        #pragma unroll
        for (int r = 0; r < 4; ++r)
          st_f32c(&P.cst[(long)ld * HSLICE + (long)(mt0 * 16 + quad * 4 + r) * H_SZ + jh],
                  c_reg[r]);
      }
    }
    gbar(P.bar, bid, bcnt);   // cst[2|3] visible before decoder l1 loads them
  }

  // ================= Decoder: 4 jobs x 128 jh-tiles, l0/l1 1-step skew ======
  {
    const int q = bid >> 7;              // 0=l0f 1=l0b 2=l1f 3=l1b
    const int layer = q >> 1, dir = q & 1;
    const int rsw = bid & 127;
    const int nidx = (rsw & 7) * 16 + (rsw >> 3);
    const int jh0 = nidx * 4;
    const int jh = jh0 + (lane & 3);
    const int mt0 = wave * 2;            // MTS=2
    const int slot = 4 + layer * 2 + dir;
    const int ld = layer * 2 + dir;

    if (layer == 0)
      stage_w2(WF, P.dw0 + (long)dir * G4 * C_IN, C_IN, C_IN,
                   P.dwh + (long)dir * G4 * H_SZ, H_SZ, H_SZ, jh0, tid);
    else
      stage_w2(WF, P.dwr + (long)dir * G4 * 1024, 1024, 1024,
                   P.dwh + (long)(2 + dir) * G4 * H_SZ, H_SZ, H_SZ, jh0, tid);
    __syncthreads();
    float b4[4], c_reg[8];
    #pragma unroll
    for (int g = 0; g < 4; ++g) b4[g] = P.bcomb[(long)slot * G4 + g * 512 + jh];
    #pragma unroll
    for (int mt = 0; mt < 2; ++mt)
      #pragma unroll
      for (int r = 0; r < 4; ++r)
        c_reg[mt * 4 + r] =
            ld_f32c(&P.cst[(long)ld * HSLICE + (long)((mt0 + mt) * 16 + quad * 4 + r) * H_SZ + jh]);

    for (int s = 0; s <= T_LEN; ++s) {
      const int p = s & 1;
      if (layer == 1 && s == 0) {
        // seed l1 h into parity 1 (step s=1 reads parity 1)
        if (tid < 64) {
          const long off = (long)(2 + dir) * HSLICE + ((long)rsw * 64 + tid) * 8;
          unsigned long long* dst = (unsigned long long*)(P.hst + HPAR + off);
          const unsigned long long* src = (const unsigned long long*)(P.hst + off);
          unsigned long long a = __hip_atomic_load(src,     __ATOMIC_RELAXED, SCOPE);
          unsigned long long b = __hip_atomic_load(src + 1, __ATOMIC_RELAXED, SCOPE);
          __hip_atomic_store(dst,     a, __ATOMIC_RELAXED, SCOPE);
          __hip_atomic_store(dst + 1, b, __ATOMIC_RELAXED, SCOPE);
        }
      } else if (layer == 0 && s < T_LEN) {
        do_step<2>(WF, P.xF + (long)s * XFT, 4,
                   P.hst + (long)p * HPAR + (long)dir * HSLICE, 16, nullptr, 0,
                   mt0, jh0, ld, p, c_reg, b4, nullptr, 0, P, lane);
      } else if (layer == 1 && s >= 1) {
        do_step<2>(WF, P.hst + (long)p * HPAR + 0 * HSLICE, 16,
                       P.hst + (long)p * HPAR + 1 * HSLICE, 16,
                       P.hst + (long)p * HPAR + (long)(2 + dir) * HSLICE, 16,
                   mt0, jh0, ld, p, c_reg, b4, nullptr, 0, P, lane);
      }
      gbar(P.bar, bid, bcnt);
    }
  }
}

// ---------------------------------------------------------------------------
__global__ void f2h(const float* __restrict__ src, _Float16* __restrict__ dst, long n) {
  for (long i = blockIdx.x * 256L + threadIdx.x; i < n; i += (long)gridDim.x * 256)
    dst[i] = (_Float16)src[i];
}

__global__ void x_to_frag(const float* __restrict__ x, _Float16* __restrict__ xF) {
  const int t = blockIdx.x, b = blockIdx.y, c = threadIdx.x;
  xF[(long)t * XFT + fragAddr(b, c)] = (_Float16)x[((long)b * T_LEN + t) * C_IN + c];
}

__global__ void h0_to_frag(const float* __restrict__ h0, _Float16* __restrict__ hstF) {
  const long i = blockIdx.x * 256L + threadIdx.x;
  const int ld = (int)(i >> 16);
  const int b = (int)((i >> 9) & 127);
  const int k = (int)(i & 511);
  hstF[(long)ld * HSLICE + fragAddr(b, k)] = (_Float16)h0[i];
}

__global__ void bias_combine(const float* __restrict__ e_bih, const float* __restrict__ e_bhh,
                             const float* __restrict__ d_bih, const float* __restrict__ d_bhh,
                             float* __restrict__ bcomb) {
  const int i = blockIdx.x * 256 + threadIdx.x;
  const int slot = i >> 11;
  const int j = i & 2047;
  float v;
  if (slot < 4) v = e_bih[slot * 2048 + j] + e_bhh[slot * 2048 + j];
  else          v = d_bih[(slot - 4) * 2048 + j] + d_bhh[(slot - 4) * 2048 + j];
  bcomb[i] = v;
}

__global__ void final_linear(const _Float16* __restrict__ hF,  // hst + HPAR
                             const float* __restrict__ lin_w, const float* __restrict__ lb,
                             float* __restrict__ out) {
  const int tid = threadIdx.x;
  const int o = tid & 127;
  const int b = blockIdx.x * 2 + (tid >> 7);
  const float* w = lin_w + (long)o * 1024;
  float acc = 0.f;
  for (int k = 0; k < H_SZ; ++k) acc += (float)hF[2L * HSLICE + fragAddr(b, k)] * w[k];
  for (int k = 0; k < H_SZ; ++k) acc += (float)hF[3L * HSLICE + fragAddr(b, k)] * w[H_SZ + k];
  out[(long)b * 128 + o] = acc + lb[o];
}

// ---------------------------------------------------------------------------
extern "C" void kernel_launch(void* const* d_in, const int* in_sizes, int n_in,
                              void* d_out, int out_size, void* d_ws, size_t ws_size,
                              hipStream_t stream) {
  (void)in_sizes; (void)n_in;
  const float* x      = (const float*)d_in[0];
  const float* h0     = (const float*)d_in[1];
  const float* c0     = (const float*)d_in[2];
  const float* e_wih0 = (const float*)d_in[3];
  const float* e_wihr = (const float*)d_in[4];
  const float* e_whh  = (const float*)d_in[5];
  const float* e_bih  = (const float*)d_in[6];
  const float* e_bhh  = (const float*)d_in[7];
  const float* dw_ih0 = (const float*)d_in[8];
  const float* dw_ihr = (const float*)d_in[9];
  const float* dw_hh  = (const float*)d_in[10];
  const float* db_ih  = (const float*)d_in[11];
  const float* db_hh  = (const float*)d_in[12];
  const float* lin_w  = (const float*)d_in[13];
  const float* lin_b  = (const float*)d_in[14];
  float* out = (float*)d_out;

  char* wsb = (char*)d_ws;
  size_t off = 0;
  auto carve = [&](size_t bytes) -> void* {
    void* pp = wsb + off;
    off += (bytes + 255) & ~(size_t)255;
    return pp;
  };
  _Float16* xF  = (_Float16*)carve((size_t)T_LEN * XFT * 2);
  _Float16* ew0 = (_Float16*)carve(2L * G4 * C_IN * 2);
  _Float16* ewr = (_Float16*)carve(2L * G4 * 1024 * 2);
  _Float16* ewh = (_Float16*)carve(4L * G4 * H_SZ * 2);
  _Float16* dw0 = (_Float16*)carve(2L * G4 * C_IN * 2);
  _Float16* dwr = (_Float16*)carve(2L * G4 * 1024 * 2);
  _Float16* dwh = (_Float16*)carve(4L * G4 * H_SZ * 2);
  _Float16* y0F = (_Float16*)carve((size_t)T_LEN * Y0T * 2);
  float* bcomb  = (float*)carve(8L * G4 * 4);
  _Float16* hst = (_Float16*)carve(2L * HPAR * 2);
  float* cst    = (float*)carve(4L * HSLICE * 4);
  unsigned int* bar = (unsigned int*)carve(2048);

  if (off > ws_size) {
    hipMemsetAsync(d_out, 0, (size_t)out_size * 4, stream);
    return;
  }

  // ---- prep ----
  hipMemsetAsync(bar, 0, 2048, stream);
  x_to_frag<<<dim3(T_LEN, B_SZ), C_IN, 0, stream>>>(x, xF);
  f2h<<<64,  256, 0, stream>>>(e_wih0, ew0, 2L * G4 * C_IN);
  f2h<<<256, 256, 0, stream>>>(e_wihr, ewr, 2L * G4 * 1024);
  f2h<<<256, 256, 0, stream>>>(e_whh,  ewh, 4L * G4 * H_SZ);
  f2h<<<64,  256, 0, stream>>>(dw_ih0, dw0, 2L * G4 * C_IN);
  f2h<<<256, 256, 0, stream>>>(dw_ihr, dwr, 2L * G4 * 1024);
  f2h<<<256, 256, 0, stream>>>(dw_hh,  dwh, 4L * G4 * H_SZ);
  h0_to_frag<<<1024, 256, 0, stream>>>(h0, hst);
  bias_combine<<<64, 256, 0, stream>>>(e_bih, e_bhh, db_ih, db_hh, bcomb);
  hipMemcpyAsync(cst, c0, 4L * HSLICE * 4, hipMemcpyDeviceToDevice, stream);

  // ---- persistent cooperative kernel (custom barriers, no grid.sync) ----
  PP P{ xF, ew0, ewr, ewh, dw0, dwr, dwh, bcomb, y0F, hst, cst, bar };
  void* kargs[] = { &P };
  hipLaunchCooperativeKernel((void*)seq_persist, dim3(512), dim3(256), kargs, 0, stream);

  // ---- final linear on decoder l1 t=511 output (parity 1, ld 2/3) ----
  final_linear<<<64, 256, 0, stream>>>(hst + HPAR, lin_w, lin_b, out);
}

// Round 7
// 17221.074 us; speedup vs baseline: 6.5367x; 1.1247x over previous
//
#include <hip/hip_runtime.h>
#include <hip/hip_cooperative_groups.h>

#define T_LEN 512
#define B_SZ  128
#define C_IN  128
#define H_SZ  512
#define G4    2048
#define HSLICE 65536   // halves per hF (ld) slice
#define HPAR  262144   // halves per parity (4 slices)
#define XFT   16384    // halves per xF[t]
#define Y0T   131072   // halves per y0F[t]

typedef _Float16 half8 __attribute__((ext_vector_type(8)));
typedef float    float4v __attribute__((ext_vector_type(4)));

#define SCOPE __HIP_MEMORY_SCOPE_AGENT

// Coherent (L2-bypass, L3-backed) helpers — relaxed: no cache flushes.
__device__ __forceinline__ half8 ld_h8c(const _Float16* p) {
  const unsigned long long* q = (const unsigned long long*)p;
  union { unsigned long long u[2]; half8 h; } v;
  v.u[0] = __hip_atomic_load(q,     __ATOMIC_RELAXED, SCOPE);
  v.u[1] = __hip_atomic_load(q + 1, __ATOMIC_RELAXED, SCOPE);
  return v.h;
}
__device__ __forceinline__ void st_u64c(unsigned long long* p, unsigned long long x) {
  __hip_atomic_store(p, x, __ATOMIC_RELAXED, SCOPE);
}

struct PP {
  const _Float16* xF;
  const _Float16 *ew0, *ewr, *ewh, *dw0, *dwr, *dwh;
  const float* bcomb;
  _Float16* y0F;
  _Float16* hst;
  float*    cst;
};

// ---- split-phase grid barrier: 16 leaves x 32 blocks, 8 per-XCD gen mirrors.
__device__ __forceinline__ void gbar_arrive(unsigned int* bar, int bid, unsigned g) {
  __syncthreads();                       // drains vmcnt: release
  if (threadIdx.x == 0) {
    unsigned old = __hip_atomic_fetch_add(bar + (bid & 15) * 16, 1u, __ATOMIC_RELAXED, SCOPE);
    if (old + 1 == 32u * g) {
      unsigned ro = __hip_atomic_fetch_add(bar + 256, 1u, __ATOMIC_RELAXED, SCOPE);
      if (ro + 1 == 16u * g) {
        #pragma unroll
        for (int i = 0; i < 8; ++i)
          __hip_atomic_store(bar + 320 + i * 16, g, __ATOMIC_RELAXED, SCOPE);
      }
    }
  }
}
__device__ __forceinline__ void gbar_wait(unsigned int* bar, int bid, unsigned g) {
  if (g && threadIdx.x == 0) {
    while (__hip_atomic_load(bar + 320 + (bid & 7) * 16, __ATOMIC_RELAXED, SCOPE) < g)
      __builtin_amdgcn_s_sleep(2);
  }
  __syncthreads();
  asm volatile("" ::: "memory");
}

// frag layout: element (m,k) at (k>>5)*4096 + (m>>4)*512 + ((k>>3)&3)*128 + (m&15)*8 + (k&7)
__device__ __forceinline__ long fragAddr(int m, int k) {
  return (long)(k >> 5) * 4096 + (m >> 4) * 512 + ((k >> 3) & 3) * 128 + (m & 15) * 8 + (k & 7);
}

// Stage 16 gate-cols of [W1;W2] (k-concat) into LDS (normal cached loads).
__device__ __forceinline__ void stage_w2(_Float16* WF,
    const _Float16* W1, long st1, int K1,
    const _Float16* W2, long st2, int K2, int jh0, int tid) {
  const int n8 = ((K1 + K2) >> 5) * 64;
  for (int idx = tid; idx < n8; idx += 256) {
    const int q = idx >> 6, l = idx & 63;
    const int c = l & 15, qd = l >> 4;
    const int j = (c >> 2) * 512 + jh0 + (c & 3);
    const int k = q * 32 + qd * 8;
    const _Float16* src = (k < K1) ? (W1 + (long)j * st1 + k)
                                   : (W2 + (long)j * st2 + (k - K1));
    *(half8*)(WF + (long)idx * 8) = *(const half8*)src;
  }
}

// MFMA over NQ k-chunks, A via normal cached loads.
template <int NQ, int MTS>
__device__ __forceinline__ void mm_norm(float4v (&acc)[MTS][2], const _Float16* WF,
                                        const _Float16* A, int mt0, int kq0, int lane) {
  const _Float16* wl = WF + lane * 8;
  const _Float16* ab = A + (long)mt0 * 512 + lane * 8;
  #pragma unroll
  for (int qq = 0; qq < NQ; ++qq) {
    const half8 bf = *(const half8*)(wl + (long)(kq0 + qq) * 512);
    #pragma unroll
    for (int mt = 0; mt < MTS; ++mt) {
      const half8 af = *(const half8*)(ab + (long)mt * 512 + (long)qq * 4096);
      acc[mt][(kq0 + qq) & 1] =
          __builtin_amdgcn_mfma_f32_16x16x32_f16(af, bf, acc[mt][(kq0 + qq) & 1], 0, 0, 0);
    }
  }
}
// MFMA over NQ k-chunks, A via coherent L3 loads (recurrent h).
template <int NQ, int MTS>
__device__ __forceinline__ void mm_coh(float4v (&acc)[MTS][2], const _Float16* WF,
                                       const _Float16* A, int mt0, int kq0, int lane) {
  const _Float16* wl = WF + lane * 8;
  const _Float16* ab = A + (long)mt0 * 512 + lane * 8;
  #pragma unroll
  for (int qq = 0; qq < NQ; ++qq) {
    const half8 bf = *(const half8*)(wl + (long)(kq0 + qq) * 512);
    #pragma unroll
    for (int mt = 0; mt < MTS; ++mt) {
      const half8 af = ld_h8c(ab + (long)mt * 512 + (long)qq * 4096);
      acc[mt][(kq0 + qq) & 1] =
          __builtin_amdgcn_mfma_f32_16x16x32_f16(af, bf, acc[mt][(kq0 + qq) & 1], 0, 0, 0);
    }
  }
}

// Cell update + packed u64 h-store (atomic) and optional y-store (normal).
template <int MTS>
__device__ __forceinline__ void cell_store(float4v (&acc)[MTS][2], int mt0, int jh0,
    float* c_reg, const float* b4, _Float16* hdst, _Float16* ydst, int ycol0, int lane) {
  const int quad = lane >> 4, jl = lane & 3;
  const bool wr = (lane & 12) == 0;
  const int sbase = (lane & 48) | jl;
  #pragma unroll
  for (int mt = 0; mt < MTS; ++mt) {
    #pragma unroll
    for (int r = 0; r < 4; ++r) {
      const float v = acc[mt][0][r] + acc[mt][1][r];
      const float iv = __shfl(v, sbase);
      const float fv = __shfl(v, sbase | 4);
      const float gv = __shfl(v, sbase | 8);
      const float ov = __shfl(v, sbase | 12);
      float h2 = 0.f;
      if (wr) {
        const float ig = iv + b4[0], fg = fv + b4[1], gg = gv + b4[2], og = ov + b4[3];
        const float si = 1.f / (1.f + __expf(-ig));
        const float sf = 1.f / (1.f + __expf(-fg));
        const float so = 1.f / (1.f + __expf(-og));
        const float eg = __expf(2.f * gg);
        const float tg = (eg - 1.f) / (eg + 1.f);
        const float c2 = sf * c_reg[mt * 4 + r] + si * tg;
        c_reg[mt * 4 + r] = c2;
        const float ec = __expf(2.f * c2);
        h2 = so * (ec - 1.f) / (ec + 1.f);
      }
      union { _Float16 f; unsigned short s; } hb; hb.f = (_Float16)h2;
      int b0 = (int)hb.s;
      int b1 = __shfl_xor(b0, 1);
      int lo = (b0 & 0xffff) | (b1 << 16);
      int hi = __shfl_xor(lo, 2);
      if ((lane & 15) == 0) {
        const unsigned long long u =
            (unsigned long long)(unsigned)lo | ((unsigned long long)(unsigned)hi << 32);
        const int m = (mt0 + mt) * 16 + quad * 4 + r;
        st_u64c((unsigned long long*)(hdst + fragAddr(m, jh0)), u);
        if (ydst) *(unsigned long long*)(ydst + fragAddr(m, ycol0)) = u;
      }
    }
  }
}

// ====================== persistent kernels ==================================
__launch_bounds__(256, 2)
__global__ void enc0_persist(PP P, unsigned int* bar) {
  const int bid = blockIdx.x, tid = threadIdx.x;
  const int wave = tid >> 6, lane = tid & 63, quad = lane >> 4;
  __shared__ _Float16 WF[24576];
  const int dir = bid >> 8, mg = (bid >> 7) & 1, rsw = bid & 127;
  const int nidx = (rsw & 7) * 16 + (rsw >> 3);
  const int jh0 = nidx * 4, jh = jh0 + (lane & 3);
  const int mt0 = mg * 4 + wave;

  stage_w2(WF, P.ew0 + (long)dir * G4 * C_IN, C_IN, C_IN,
               P.ewh + (long)dir * G4 * H_SZ, H_SZ, H_SZ, jh0, tid);
  __syncthreads();
  float b4[4], c_reg[4];
  #pragma unroll
  for (int g = 0; g < 4; ++g) b4[g] = P.bcomb[(long)dir * G4 + g * 512 + jh];
  #pragma unroll
  for (int r = 0; r < 4; ++r)
    c_reg[r] = P.cst[(long)dir * HSLICE + (long)(mt0 * 16 + quad * 4 + r) * H_SZ + jh];

  for (int s = 0; s < T_LEN; ++s) {
    const int p = s & 1;
    const int td = dir ? (T_LEN - 1 - s) : s;
    float4v acc[1][2] = {};
    mm_norm<4, 1>(acc, WF, P.xF + (long)td * XFT, mt0, 0, lane);     // overlap zone
    gbar_wait(bar, bid, s);
    mm_coh<16, 1>(acc, WF, P.hst + (long)p * HPAR + (long)dir * HSLICE, mt0, 4, lane);
    cell_store<1>(acc, mt0, jh0, c_reg, b4,
                  P.hst + (long)(1 - p) * HPAR + (long)dir * HSLICE,
                  P.y0F + (long)td * Y0T, dir * 512 + jh0, lane);
    gbar_arrive(bar, bid, s + 1);
  }
  if ((lane & 12) == 0) {
    #pragma unroll
    for (int r = 0; r < 4; ++r)
      P.cst[(long)dir * HSLICE + (long)(mt0 * 16 + quad * 4 + r) * H_SZ + jh] = c_reg[r];
  }
}

__launch_bounds__(256, 2)
__global__ void enc1_persist(PP P, unsigned int* bar) {
  const int bid = blockIdx.x, tid = threadIdx.x;
  const int wave = tid >> 6, lane = tid & 63, quad = lane >> 4;
  __shared__ _Float16 WF[24576];
  const int dir = bid >> 8, mg = (bid >> 7) & 1, rsw = bid & 127;
  const int nidx = (rsw & 7) * 16 + (rsw >> 3);
  const int jh0 = nidx * 4, jh = jh0 + (lane & 3);
  const int mt0 = mg * 4 + wave;
  const int ld = 2 + dir;

  stage_w2(WF, P.ewr + (long)dir * G4 * 1024, 1024, 1024,
               P.ewh + (long)ld * G4 * H_SZ, H_SZ, H_SZ, jh0, tid);
  __syncthreads();
  float b4[4], c_reg[4];
  #pragma unroll
  for (int g = 0; g < 4; ++g) b4[g] = P.bcomb[(long)ld * G4 + g * 512 + jh];
  #pragma unroll
  for (int r = 0; r < 4; ++r)
    c_reg[r] = P.cst[(long)ld * HSLICE + (long)(mt0 * 16 + quad * 4 + r) * H_SZ + jh];

  for (int s = 0; s < T_LEN; ++s) {
    const int p = s & 1;
    const int td = dir ? (T_LEN - 1 - s) : s;
    float4v acc[1][2] = {};
    mm_norm<32, 1>(acc, WF, P.y0F + (long)td * Y0T, mt0, 0, lane);   // overlap zone
    gbar_wait(bar, bid, s);
    mm_coh<16, 1>(acc, WF, P.hst + (long)p * HPAR + (long)ld * HSLICE, mt0, 32, lane);
    cell_store<1>(acc, mt0, jh0, c_reg, b4,
                  P.hst + (long)(1 - p) * HPAR + (long)ld * HSLICE, nullptr, 0, lane);
    gbar_arrive(bar, bid, s + 1);
  }
  if ((lane & 12) == 0) {
    #pragma unroll
    for (int r = 0; r < 4; ++r)
      P.cst[(long)ld * HSLICE + (long)(mt0 * 16 + quad * 4 + r) * H_SZ + jh] = c_reg[r];
  }
}

__launch_bounds__(256, 2)
__global__ void dec_persist(PP P, unsigned int* bar) {
  const int bid = blockIdx.x, tid = threadIdx.x;
  const int wave = tid >> 6, lane = tid & 63, quad = lane >> 4;
  __shared__ _Float16 WF[24576];
  const int q = bid >> 7;              // 0=l0f 1=l0b 2=l1f 3=l1b
  const int layer = q >> 1, dir = q & 1;
  const int rsw = bid & 127;
  const int nidx = (rsw & 7) * 16 + (rsw >> 3);
  const int jh0 = nidx * 4, jh = jh0 + (lane & 3);
  const int mt0 = wave * 2;            // MTS=2
  const int slot = 4 + layer * 2 + dir;
  const int ld = layer * 2 + dir;

  if (layer == 0)
    stage_w2(WF, P.dw0 + (long)dir * G4 * C_IN, C_IN, C_IN,
                 P.dwh + (long)dir * G4 * H_SZ, H_SZ, H_SZ, jh0, tid);
  else
    stage_w2(WF, P.dwr + (long)dir * G4 * 1024, 1024, 1024,
                 P.dwh + (long)ld * G4 * H_SZ, H_SZ, H_SZ, jh0, tid);
  __syncthreads();
  float b4[4], c_reg[8];
  #pragma unroll
  for (int g = 0; g < 4; ++g) b4[g] = P.bcomb[(long)slot * G4 + g * 512 + jh];
  #pragma unroll
  for (int mt = 0; mt < 2; ++mt)
    #pragma unroll
    for (int r = 0; r < 4; ++r)
      c_reg[mt * 4 + r] =
          P.cst[(long)ld * HSLICE + (long)((mt0 + mt) * 16 + quad * 4 + r) * H_SZ + jh];

  for (int s = 0; s <= T_LEN; ++s) {
    const int p = s & 1;
    float4v acc[2][2] = {};
    if (layer == 0 && s < T_LEN)
      mm_norm<4, 2>(acc, WF, P.xF + (long)s * XFT, mt0, 0, lane);    // overlap zone
    gbar_wait(bar, bid, s);
    if (layer == 0) {
      if (s < T_LEN) {
        mm_coh<16, 2>(acc, WF, P.hst + (long)p * HPAR + (long)dir * HSLICE, mt0, 4, lane);
        cell_store<2>(acc, mt0, jh0, c_reg, b4,
                      P.hst + (long)(1 - p) * HPAR + (long)dir * HSLICE, nullptr, 0, lane);
      }
    } else {
      if (s == 0) {
        // seed own h into parity 1 (step s=1 reads parity 1); src from prev kernel.
        if (tid < 64) {
          const long off = (long)(2 + dir) * HSLICE + ((long)rsw * 64 + tid) * 8;
          const unsigned long long* src = (const unsigned long long*)(P.hst + off);
          st_u64c((unsigned long long*)(P.hst + HPAR + off),     src[0]);
          st_u64c((unsigned long long*)(P.hst + HPAR + off) + 1, src[1]);
        }
      } else {
        mm_coh<16, 2>(acc, WF, P.hst + (long)p * HPAR + 0 * HSLICE, mt0, 0, lane);
        mm_coh<16, 2>(acc, WF, P.hst + (long)p * HPAR + 1 * HSLICE, mt0, 16, lane);
        mm_coh<16, 2>(acc, WF, P.hst + (long)p * HPAR + (long)(2 + dir) * HSLICE, mt0, 32, lane);
        cell_store<2>(acc, mt0, jh0, c_reg, b4,
                      P.hst + (long)(1 - p) * HPAR + (long)(2 + dir) * HSLICE, nullptr, 0, lane);
      }
    }
    gbar_arrive(bar, bid, s + 1);
  }
}

// ---------------------------------------------------------------------------
__global__ void f2h(const float* __restrict__ src, _Float16* __restrict__ dst, long n) {
  for (long i = blockIdx.x * 256L + threadIdx.x; i < n; i += (long)gridDim.x * 256)
    dst[i] = (_Float16)src[i];
}

__global__ void x_to_frag(const float* __restrict__ x, _Float16* __restrict__ xF) {
  const int t = blockIdx.x, b = blockIdx.y, c = threadIdx.x;
  xF[(long)t * XFT + fragAddr(b, c)] = (_Float16)x[((long)b * T_LEN + t) * C_IN + c];
}

__global__ void h0_to_frag(const float* __restrict__ h0, _Float16* __restrict__ hstF) {
  const long i = blockIdx.x * 256L + threadIdx.x;
  const int ld = (int)(i >> 16);
  const int b = (int)((i >> 9) & 127);
  const int k = (int)(i & 511);
  hstF[(long)ld * HSLICE + fragAddr(b, k)] = (_Float16)h0[i];
}

__global__ void bias_combine(const float* __restrict__ e_bih, const float* __restrict__ e_bhh,
                             const float* __restrict__ d_bih, const float* __restrict__ d_bhh,
                             float* __restrict__ bcomb) {
  const int i = blockIdx.x * 256 + threadIdx.x;
  const int slot = i >> 11;
  const int j = i & 2047;
  float v;
  if (slot < 4) v = e_bih[slot * 2048 + j] + e_bhh[slot * 2048 + j];
  else          v = d_bih[(slot - 4) * 2048 + j] + d_bhh[(slot - 4) * 2048 + j];
  bcomb[i] = v;
}

__global__ void final_linear(const _Float16* __restrict__ hF,  // hst + HPAR
                             const float* __restrict__ lin_w, const float* __restrict__ lb,
                             float* __restrict__ out) {
  const int tid = threadIdx.x;
  const int o = tid & 127;
  const int b = blockIdx.x * 2 + (tid >> 7);
  const float* w = lin_w + (long)o * 1024;
  float acc = 0.f;
  for (int k = 0; k < H_SZ; ++k) acc += (float)hF[2L * HSLICE + fragAddr(b, k)] * w[k];
  for (int k = 0; k < H_SZ; ++k) acc += (float)hF[3L * HSLICE + fragAddr(b, k)] * w[H_SZ + k];
  out[(long)b * 128 + o] = acc + lb[o];
}

// ---------------------------------------------------------------------------
extern "C" void kernel_launch(void* const* d_in, const int* in_sizes, int n_in,
                              void* d_out, int out_size, void* d_ws, size_t ws_size,
                              hipStream_t stream) {
  (void)in_sizes; (void)n_in;
  const float* x      = (const float*)d_in[0];
  const float* h0     = (const float*)d_in[1];
  const float* c0     = (const float*)d_in[2];
  const float* e_wih0 = (const float*)d_in[3];
  const float* e_wihr = (const float*)d_in[4];
  const float* e_whh  = (const float*)d_in[5];
  const float* e_bih  = (const float*)d_in[6];
  const float* e_bhh  = (const float*)d_in[7];
  const float* dw_ih0 = (const float*)d_in[8];
  const float* dw_ihr = (const float*)d_in[9];
  const float* dw_hh  = (const float*)d_in[10];
  const float* db_ih  = (const float*)d_in[11];
  const float* db_hh  = (const float*)d_in[12];
  const float* lin_w  = (const float*)d_in[13];
  const float* lin_b  = (const float*)d_in[14];
  float* out = (float*)d_out;

  char* wsb = (char*)d_ws;
  size_t off = 0;
  auto carve = [&](size_t bytes) -> void* {
    void* pp = wsb + off;
    off += (bytes + 255) & ~(size_t)255;
    return pp;
  };
  _Float16* xF  = (_Float16*)carve((size_t)T_LEN * XFT * 2);
  _Float16* ew0 = (_Float16*)carve(2L * G4 * C_IN * 2);
  _Float16* ewr = (_Float16*)carve(2L * G4 * 1024 * 2);
  _Float16* ewh = (_Float16*)carve(4L * G4 * H_SZ * 2);
  _Float16* dw0 = (_Float16*)carve(2L * G4 * C_IN * 2);
  _Float16* dwr = (_Float16*)carve(2L * G4 * 1024 * 2);
  _Float16* dwh = (_Float16*)carve(4L * G4 * H_SZ * 2);
  _Float16* y0F = (_Float16*)carve((size_t)T_LEN * Y0T * 2);
  float* bcomb  = (float*)carve(8L * G4 * 4);
  _Float16* hst = (_Float16*)carve(2L * HPAR * 2);
  float* cst    = (float*)carve(4L * HSLICE * 4);
  unsigned int* bar0 = (unsigned int*)carve(2048);
  unsigned int* bar1 = (unsigned int*)carve(2048);
  unsigned int* bar2 = (unsigned int*)carve(2048);

  if (off > ws_size) {
    hipMemsetAsync(d_out, 0, (size_t)out_size * 4, stream);
    return;
  }

  // ---- prep ----
  hipMemsetAsync(bar0, 0, 3 * 2048, stream);
  x_to_frag<<<dim3(T_LEN, B_SZ), C_IN, 0, stream>>>(x, xF);
  f2h<<<64,  256, 0, stream>>>(e_wih0, ew0, 2L * G4 * C_IN);
  f2h<<<256, 256, 0, stream>>>(e_wihr, ewr, 2L * G4 * 1024);
  f2h<<<256, 256, 0, stream>>>(e_whh,  ewh, 4L * G4 * H_SZ);
  f2h<<<64,  256, 0, stream>>>(dw_ih0, dw0, 2L * G4 * C_IN);
  f2h<<<256, 256, 0, stream>>>(dw_ihr, dwr, 2L * G4 * 1024);
  f2h<<<256, 256, 0, stream>>>(dw_hh,  dwh, 4L * G4 * H_SZ);
  h0_to_frag<<<1024, 256, 0, stream>>>(h0, hst);
  bias_combine<<<64, 256, 0, stream>>>(e_bih, e_bhh, db_ih, db_hh, bcomb);
  hipMemcpyAsync(cst, c0, 4L * HSLICE * 4, hipMemcpyDeviceToDevice, stream);

  // ---- three persistent cooperative kernels (split-phase barriers) ----
  PP P{ xF, ew0, ewr, ewh, dw0, dwr, dwh, bcomb, y0F, hst, cst };
  {
    void* a0[] = { &P, &bar0 };
    hipLaunchCooperativeKernel((void*)enc0_persist, dim3(512), dim3(256), a0, 0, stream);
    void* a1[] = { &P, &bar1 };
    hipLaunchCooperativeKernel((void*)enc1_persist, dim3(512), dim3(256), a1, 0, stream);
    void* a2[] = { &P, &bar2 };
    hipLaunchCooperativeKernel((void*)dec_persist, dim3(512), dim3(256), a2, 0, stream);
  }

  // ---- final linear on decoder l1 t=511 output (parity 1, ld 2/3) ----
  final_linear<<<64, 256, 0, stream>>>(hst + HPAR, lin_w, lin_b, out);
}